// Round 6
// baseline (199.214 us; speedup 1.0000x reference)
//
#include <hip/hip_runtime.h>
#include <cstdint>
#include <cstddef>

constexpr int Bn = 64;     // batch
constexpr int Nn = 1024;   // nodes per graph
constexpr int Dn = 1024;   // input feature dim
constexpr int Cn = 128;    // hidden channels
constexpr int En = 16384;  // edges per graph

typedef short s16x8 __attribute__((ext_vector_type(8)));   // 8 bf16 = 4 VGPR (MFMA A/B frag)
typedef float f32x4 __attribute__((ext_vector_type(4)));   // MFMA C/D frag

__device__ __forceinline__ uint32_t f2bf(float f) {        // fp32 -> bf16 bits, RNE
    uint32_t u = __float_as_uint(f);
    return (u + 0x7fffu + ((u >> 16) & 1u)) >> 16;
}

// ---------------- prep: zero indeg | int64-detect | Wc -> bf16 transposed ----------------
// blocks 0..3: zero indeg; 4..67: detect; 68..131: wconv.
// meta[1]==1 iff int32 edge data detected (ws poisoned 0xAA; all writers store 1 -> benign race).
__global__ __launch_bounds__(256) void k_prep(const int* __restrict__ ei32,
                                              const float* __restrict__ Wc,
                                              int* __restrict__ indeg,
                                              int* __restrict__ meta,
                                              unsigned short* __restrict__ Wt) {
    int bid = blockIdx.x, tid = threadIdx.x;
    if (bid < 4) {
        indeg[bid * 256 + tid] = 0;
    } else if (bid < 68) {
        __shared__ int sh;
        if (tid == 0) sh = 0;
        __syncthreads();
        int i = (bid - 4) * 256 + tid;          // [0, 16384)
        if (ei32[2 * i + 1]) atomicOr(&sh, 1);
        __syncthreads();
        if (tid == 0 && sh) meta[1] = 1;
    } else {
        int i = (bid - 68) * 256 + tid;         // [0, 16384)
        int n = i >> 7, k = i & 127;
        Wt[i] = (unsigned short)f2bf(Wc[k * Cn + n]);
    }
}

__global__ void k_hist(const int* __restrict__ ei32, const int* __restrict__ meta,
                       int* __restrict__ indeg) {
    int e = blockIdx.x * 256 + threadIdx.x;
    bool i64 = (meta[1] != 1);
    int dst = ei32[i64 ? 2 * (En + e) : (En + e)] & (Nn - 1);
    atomicAdd(&indeg[dst], 1);
}

__global__ __launch_bounds__(1024) void k_scan(const int* __restrict__ indeg,
                                               int* __restrict__ offs,
                                               int* __restrict__ cursor) {
    __shared__ int tmp[Nn];
    int t = threadIdx.x;
    int v = indeg[t];
    tmp[t] = v;
    __syncthreads();
    for (int off = 1; off < Nn; off <<= 1) {
        int add = (t >= off) ? tmp[t - off] : 0;
        __syncthreads();
        tmp[t] += add;
        __syncthreads();
    }
    offs[t + 1] = tmp[t];
    if (t == 0) offs[0] = 0;
    cursor[t] = tmp[t] - v;   // exclusive prefix
}

__global__ void k_scatter(const int* __restrict__ ei32, const int* __restrict__ meta,
                          int* __restrict__ cursor, int* __restrict__ ssrc) {
    int e = blockIdx.x * 256 + threadIdx.x;
    bool i64 = (meta[1] != 1);
    int src = ei32[i64 ? 2 * e : e] & (Nn - 1);
    int dst = ei32[i64 ? 2 * (En + e) : (En + e)] & (Nn - 1);
    int pos = atomicAdd(&cursor[dst], 1);
    if (pos >= 0 && pos < En) ssrc[pos] = src;
}

// ---------------- embedding stage A: partial dots ----------------
__global__ __launch_bounds__(256) void k_embedA(const float* __restrict__ x,
                                                const float* __restrict__ We,
                                                float* __restrict__ pws) {
    __shared__ float sx[256];
    __shared__ float sp[256];
    int bid = blockIdx.x, tid = threadIdx.x;
    int b = bid >> 2, q = bid & 3;
    int c = tid & 127, h2 = tid >> 7;
    sx[tid] = x[b * Dn + q * 256 + tid];
    __syncthreads();
    float acc = 0.f;
    int d0 = q * 256 + h2 * 128;
    int dl = h2 * 128;
#pragma unroll 8
    for (int i = 0; i < 128; ++i) acc += sx[dl + i] * We[(d0 + i) * Cn + c];
    sp[h2 * 128 + c] = acc;
    __syncthreads();
    if (h2 == 0) pws[(b * 4 + q) * Cn + c] = sp[c] + sp[128 + c];
}

// ---------------- stage B: blocks 0..63: g = relu(sum partials + be) @ Wc;
//                  blocks 64..191: edeg[e] = (float)indeg[ssrc[e]] ----------------
__global__ __launch_bounds__(128) void k_g(const float* __restrict__ pws,
                                           const float* __restrict__ be,
                                           const float* __restrict__ Wc,
                                           const int* __restrict__ indeg,
                                           const int* __restrict__ ssrc,
                                           float* __restrict__ g,
                                           float* __restrict__ edeg) {
    int bid = blockIdx.x, t = threadIdx.x;
    if (bid >= 64) {
        int i = (bid - 64) * 128 + t;    // [0, 16384)
        edeg[i] = (float)indeg[ssrc[i]];
        return;
    }
    __shared__ float se[Cn];
    int b = bid, c = t;
    float e = pws[(b * 4 + 0) * Cn + c] + pws[(b * 4 + 1) * Cn + c] +
              pws[(b * 4 + 2) * Cn + c] + pws[(b * 4 + 3) * Cn + c] + be[c];
    se[c] = fmaxf(e, 0.f);
    __syncthreads();
    float ga = 0.f;
#pragma unroll 8
    for (int k = 0; k < Cn; ++k) ga += se[k] * Wc[k * Cn + c];
    g[b * Cn + c] = ga;
}

constexpr int PAD = 136;     // LDS row stride in bf16 elems
constexpr int ECHUNK = 768;  // edge staging chunk

// ---------------- conv 1+2 fused: agg[dst,c] = sum_src relu(edeg*g[b,c]+bc[c]);
//                  hn = relu(agg @ Wc + bc), fp32 out ----------------
__global__ __launch_bounds__(256, 4) void k_conv2f(const float* __restrict__ g,
                                                   float* __restrict__ hn,
                                                   const unsigned short* __restrict__ Wt,
                                                   const float* __restrict__ bc,
                                                   const int* __restrict__ offs,
                                                   const float* __restrict__ edeg,
                                                   int swz) {
    __shared__ unsigned short sSb[32 * PAD];   // 8.7 KB
    __shared__ float sDeg[ECHUNK];             // 3 KB
    int tid = threadIdx.x, bidx = blockIdx.x;
    int b, dst0;
    if (swz) {
        int xcd = bidx & 7, q = bidx >> 3;
        b = xcd * 8 + (q >> 5);
        dst0 = (q & 31) * 32;
    } else {
        b = bidx >> 5;
        dst0 = (bidx & 31) * 32;
    }

    int c2 = tid & 63, u = tid >> 6;
    float gx = g[b * Cn + 2 * c2], gy = g[b * Cn + 2 * c2 + 1];
    float bx = bc[2 * c2], by = bc[2 * c2 + 1];
    float aL[8], aH[8];
#pragma unroll
    for (int t0 = 0; t0 < 8; ++t0) { aL[t0] = 0.f; aH[t0] = 0.f; }

    int e_begin = offs[dst0], e_end = offs[dst0 + 32];
    for (int base = e_begin; base < e_end; base += ECHUNK) {
        int cnt = e_end - base; if (cnt > ECHUNK) cnt = ECHUNK;
        __syncthreads();
        for (int i = tid; i < cnt; i += 256) sDeg[i] = edeg[base + i];
        __syncthreads();
#pragma unroll
        for (int t0 = 0; t0 < 8; ++t0) {
            int dst = dst0 + u * 8 + t0;
            int lo = offs[dst], hi = offs[dst + 1];
            int j0 = (lo > base ? lo : base) - base;
            int j1 = ((hi < base + cnt) ? hi : base + cnt) - base;
            float s0 = aL[t0], s1 = aH[t0];
            for (int j = j0; j < j1; ++j) {
                float d = sDeg[j];
                s0 += fmaxf(fmaf(d, gx, bx), 0.f);
                s1 += fmaxf(fmaf(d, gy, by), 0.f);
            }
            aL[t0] = s0; aH[t0] = s1;
        }
    }
#pragma unroll
    for (int t0 = 0; t0 < 8; ++t0) {
        int row = u * 8 + t0;
        *(uint32_t*)&sSb[row * PAD + 2 * c2] = f2bf(aL[t0]) | (f2bf(aH[t0]) << 16);
    }

    // B-fragments from global Wt (32 KB, L2-hot)
    int lane = tid & 63, w = tid >> 6;
    int m = lane & 15, quad = lane >> 4;
    s16x8 bf0[4], bf1[4];
#pragma unroll
    for (int ks = 0; ks < 4; ++ks) {
        int ko = ks * 32 + quad * 8;
        bf0[ks] = *(const s16x8*)&Wt[(w * 32 + m) * Cn + ko];
        bf1[ks] = *(const s16x8*)&Wt[(w * 32 + 16 + m) * Cn + ko];
    }
    __syncthreads();

    f32x4 acc[2][2];
#pragma unroll
    for (int rt = 0; rt < 2; ++rt)
#pragma unroll
        for (int ct = 0; ct < 2; ++ct) acc[rt][ct] = (f32x4){0.f, 0.f, 0.f, 0.f};
#pragma unroll
    for (int ks = 0; ks < 4; ++ks) {
        int ko = ks * 32 + quad * 8;
        s16x8 a0 = *(const s16x8*)&sSb[(0 * 16 + m) * PAD + ko];
        s16x8 a1 = *(const s16x8*)&sSb[(1 * 16 + m) * PAD + ko];
        acc[0][0] = __builtin_amdgcn_mfma_f32_16x16x32_bf16(a0, bf0[ks], acc[0][0], 0, 0, 0);
        acc[0][1] = __builtin_amdgcn_mfma_f32_16x16x32_bf16(a0, bf1[ks], acc[0][1], 0, 0, 0);
        acc[1][0] = __builtin_amdgcn_mfma_f32_16x16x32_bf16(a1, bf0[ks], acc[1][0], 0, 0, 0);
        acc[1][1] = __builtin_amdgcn_mfma_f32_16x16x32_bf16(a1, bf1[ks], acc[1][1], 0, 0, 0);
    }

    float* ob = hn + ((size_t)b * Nn + dst0) * Cn;
#pragma unroll
    for (int rt = 0; rt < 2; ++rt)
#pragma unroll
        for (int ct = 0; ct < 2; ++ct) {
            int col = w * 32 + ct * 16 + m;
            float bias = bc[col];
#pragma unroll
            for (int reg = 0; reg < 4; ++reg) {
                int row = rt * 16 + quad * 4 + reg;
                ob[row * Cn + col] = fmaxf(acc[rt][ct][reg] + bias, 0.f);
            }
        }
}

// ---------------- general conv: hn = relu((A h) @ Wc + bc), fp32 h gather (float4/lane) ----------------
// thread map: c4 = tid&31 (channels 4c4..4c4+3), u = tid>>5 in [0,8): rows u*4..u*4+3
__global__ __launch_bounds__(256, 4) void k_conv(const float* __restrict__ h,
                                                 float* __restrict__ hn,
                                                 const unsigned short* __restrict__ Wt,
                                                 const float* __restrict__ bc,
                                                 const int* __restrict__ offs,
                                                 const int* __restrict__ ssrc,
                                                 int swz) {
    __shared__ unsigned short sSb[32 * PAD];   // 8.7 KB
    __shared__ int sIdx[ECHUNK];               // 3 KB
    int tid = threadIdx.x, bidx = blockIdx.x;
    int b, dst0;
    if (swz) {
        int xcd = bidx & 7, q = bidx >> 3;
        b = xcd * 8 + (q >> 5);
        dst0 = (q & 31) * 32;
    } else {
        b = bidx >> 5;
        dst0 = (bidx & 31) * 32;
    }

    int c4 = tid & 31, u = tid >> 5;
    const float4* hb4 = (const float4*)(h + (size_t)b * (Nn * Cn));
    float4 acc4[4];
#pragma unroll
    for (int t0 = 0; t0 < 4; ++t0) acc4[t0] = (float4){0.f, 0.f, 0.f, 0.f};

    int e_begin = offs[dst0], e_end = offs[dst0 + 32];
    for (int base = e_begin; base < e_end; base += ECHUNK) {
        int cnt = e_end - base; if (cnt > ECHUNK) cnt = ECHUNK;
        __syncthreads();
        for (int i = tid; i < cnt; i += 256) sIdx[i] = ssrc[base + i];
        __syncthreads();
#pragma unroll
        for (int t0 = 0; t0 < 4; ++t0) {
            int dst = dst0 + u * 4 + t0;
            int lo = offs[dst], hi = offs[dst + 1];
            int j0 = (lo > base ? lo : base) - base;
            int j1 = ((hi < base + cnt) ? hi : base + cnt) - base;
            float4 a = acc4[t0];
            int j = j0;
            for (; j + 4 <= j1; j += 4) {
                float4 v0 = hb4[sIdx[j + 0] * 32 + c4];
                float4 v1 = hb4[sIdx[j + 1] * 32 + c4];
                float4 v2 = hb4[sIdx[j + 2] * 32 + c4];
                float4 v3 = hb4[sIdx[j + 3] * 32 + c4];
                a.x += (v0.x + v1.x) + (v2.x + v3.x);
                a.y += (v0.y + v1.y) + (v2.y + v3.y);
                a.z += (v0.z + v1.z) + (v2.z + v3.z);
                a.w += (v0.w + v1.w) + (v2.w + v3.w);
            }
            for (; j < j1; ++j) {
                float4 v = hb4[sIdx[j] * 32 + c4];
                a.x += v.x; a.y += v.y; a.z += v.z; a.w += v.w;
            }
            acc4[t0] = a;
        }
    }
    // write aggregated tile as bf16 into sSb (4 ch -> 2 packed words, 8 B store)
#pragma unroll
    for (int t0 = 0; t0 < 4; ++t0) {
        int row = u * 4 + t0;
        uint2 pk;
        pk.x = f2bf(acc4[t0].x) | (f2bf(acc4[t0].y) << 16);
        pk.y = f2bf(acc4[t0].z) | (f2bf(acc4[t0].w) << 16);
        *(uint2*)&sSb[row * PAD + c4 * 4] = pk;
    }

    // B-fragments from global Wt (32 KB, L2-hot)
    int lane = tid & 63, w = tid >> 6;
    int m = lane & 15, quad = lane >> 4;
    s16x8 bf0[4], bf1[4];
#pragma unroll
    for (int ks = 0; ks < 4; ++ks) {
        int ko = ks * 32 + quad * 8;
        bf0[ks] = *(const s16x8*)&Wt[(w * 32 + m) * Cn + ko];
        bf1[ks] = *(const s16x8*)&Wt[(w * 32 + 16 + m) * Cn + ko];
    }
    __syncthreads();

    f32x4 accm[2][2];
#pragma unroll
    for (int rt = 0; rt < 2; ++rt)
#pragma unroll
        for (int ct = 0; ct < 2; ++ct) accm[rt][ct] = (f32x4){0.f, 0.f, 0.f, 0.f};
#pragma unroll
    for (int ks = 0; ks < 4; ++ks) {
        int ko = ks * 32 + quad * 8;
        s16x8 a0 = *(const s16x8*)&sSb[(0 * 16 + m) * PAD + ko];
        s16x8 a1 = *(const s16x8*)&sSb[(1 * 16 + m) * PAD + ko];
        accm[0][0] = __builtin_amdgcn_mfma_f32_16x16x32_bf16(a0, bf0[ks], accm[0][0], 0, 0, 0);
        accm[0][1] = __builtin_amdgcn_mfma_f32_16x16x32_bf16(a0, bf1[ks], accm[0][1], 0, 0, 0);
        accm[1][0] = __builtin_amdgcn_mfma_f32_16x16x32_bf16(a1, bf0[ks], accm[1][0], 0, 0, 0);
        accm[1][1] = __builtin_amdgcn_mfma_f32_16x16x32_bf16(a1, bf1[ks], accm[1][1], 0, 0, 0);
    }

    float* ob = hn + ((size_t)b * Nn + dst0) * Cn;
#pragma unroll
    for (int rt = 0; rt < 2; ++rt)
#pragma unroll
        for (int ct = 0; ct < 2; ++ct) {
            int col = w * 32 + ct * 16 + m;
            float bias = bc[col];
#pragma unroll
            for (int reg = 0; reg < 4; ++reg) {
                int row = rt * 16 + quad * 4 + reg;
                ob[row * Cn + col] = fmaxf(accm[rt][ct][reg] + bias, 0.f);
            }
        }
}

// ---------------- classifier: out[b] = h[b*N + 0] . W_cls + b_cls ----------------
__global__ __launch_bounds__(128) void k_cls(const float* __restrict__ h,
                                             const float* __restrict__ Wcls,
                                             const float* __restrict__ bcls,
                                             float* __restrict__ out) {
    __shared__ float red[128];
    int b = blockIdx.x, t = threadIdx.x;
    red[t] = h[(size_t)b * Nn * Cn + t] * Wcls[t];
    __syncthreads();
    for (int s = 64; s > 0; s >>= 1) {
        if (t < s) red[t] += red[t + s];
        __syncthreads();
    }
    if (t == 0) out[b] = red[0] + bcls[0];
}

extern "C" void kernel_launch(void* const* d_in, const int* in_sizes, int n_in,
                              void* d_out, int out_size, void* d_ws, size_t ws_size,
                              hipStream_t stream) {
    const float* x    = (const float*)d_in[0];
    const int*   ei32 = (const int*)d_in[1];
    const float* We   = (const float*)d_in[2];
    const float* be   = (const float*)d_in[3];
    const float* Wc   = (const float*)d_in[4];
    const float* bc   = (const float*)d_in[5];
    const float* Wcls = (const float*)d_in[6];
    const float* bcls = (const float*)d_in[7];
    float* out = (float*)d_out;

    // ---- workspace layout ----
    // 0       g      32768   (B x C fp32)
    // 32768   indeg   4096
    // 36864   meta    4096   (meta[1] == 1 iff int32 edge data)
    // 40960   offs    8192
    // 49152   cursor  4096
    // 53248   ssrc   65536
    // 118784  edeg   65536   (fp32 degree per CSR-ordered edge)
    // 184320  Wt     32768   (128x128 bf16, transposed)
    // 217088  pws   131072   (embed partials)
    // 348160  heap: ping-pong fp32 h buffers (G*N*C*4 B each)
    constexpr size_t WS_FIXED = 348160;
    char* ws = (char*)d_ws;
    float*          g      = (float*)(ws + 0);
    int*            indeg  = (int*)(ws + 32768);
    int*            meta   = (int*)(ws + 36864);
    int*            offs   = (int*)(ws + 40960);
    int*            cursor = (int*)(ws + 49152);
    int*            ssrc   = (int*)(ws + 53248);
    float*          edeg   = (float*)(ws + 118784);
    unsigned short* Wt     = (unsigned short*)(ws + 184320);
    float*          pws    = (float*)(ws + 217088);

    size_t per = (size_t)Nn * Cn * 4;     // 512 KB per sample (fp32)
    size_t avail = (ws_size > WS_FIXED) ? (ws_size - WS_FIXED) : 0;
    int G = (int)(avail / (2 * per));
    if (G > Bn) G = Bn;
    if (G < 1) G = 1;
    float* hA = (float*)(ws + WS_FIXED);
    float* hB = hA + (size_t)G * Nn * Cn;

    k_prep<<<132, 256, 0, stream>>>(ei32, Wc, indeg, meta, Wt);
    k_hist<<<64, 256, 0, stream>>>(ei32, meta, indeg);
    k_scan<<<1, 1024, 0, stream>>>(indeg, offs, cursor);
    k_scatter<<<64, 256, 0, stream>>>(ei32, meta, cursor, ssrc);
    k_embedA<<<256, 256, 0, stream>>>(x, We, pws);
    k_g<<<192, 128, 0, stream>>>(pws, be, Wc, indeg, ssrc, g, edeg);

    for (int b0 = 0; b0 < Bn; b0 += G) {
        int gc = (Bn - b0 < G) ? (Bn - b0) : G;
        int swz = (gc == 64) ? 1 : 0;
        k_conv2f<<<gc * 32, 256, 0, stream>>>(g + b0 * Cn, hA, Wt, bc, offs, edeg, swz);
        k_conv<<<gc * 32, 256, 0, stream>>>(hA, hB, Wt, bc, offs, ssrc, swz);
        k_conv<<<gc * 32, 256, 0, stream>>>(hB, hA, Wt, bc, offs, ssrc, swz);
        k_cls<<<gc, 128, 0, stream>>>(hA, Wcls, bcls, out + b0);
    }
}